// Round 7
// baseline (473.990 us; speedup 1.0000x reference)
//
#include <hip/hip_runtime.h>
#include <math.h>

#define DIM 128
#define TPB 256
#define PREP_GRID 2048

// ---------- prep: sim partials + diff precompute + row histogram ----------
__global__ void prep_kernel(const float* __restrict__ inputs,
                            const float* __restrict__ old_act,
                            const int* __restrict__ fields,
                            const int* __restrict__ sub_rows, int e_sub,
                            const int* __restrict__ sup_rows, int e_sup,
                            int* __restrict__ cnt,            // [2*nrows] pre-zeroed
                            float* __restrict__ partials,     // [PREP_GRID*3]
                            float* __restrict__ diff,         // [n]
                            int nrows, int n2) {
    int tid = blockIdx.x * blockDim.x + threadIdx.x;
    int stride = gridDim.x * blockDim.x;

    float dot = 0.f, nx = 0.f, ny = 0.f;
    for (int i = tid; i < n2; i += stride) {
        int idx = i * 2;
        int b = idx >> 7, d = idx & (DIM - 1);
        float2 x = *(const float2*)(inputs + idx);
        int f = fields[b];
        float2 y = *(const float2*)(old_act + (size_t)f * DIM + d);
        dot += x.x * y.x + x.y * y.y;
        nx  += x.x * x.x + x.y * x.y;
        ny  += y.x * y.x + y.y * y.y;
        *(float2*)(diff + idx) = make_float2(x.x - y.x, x.y - y.y);
    }
    int e_tot = e_sub + e_sup;
    for (int i = tid; i < e_tot; i += stride) {
        int r = (i < e_sub) ? sub_rows[i] : (nrows + sup_rows[i - e_sub]);
        atomicAdd(&cnt[r], 1);
    }
    for (int off = 32; off > 0; off >>= 1) {
        dot += __shfl_down(dot, off, 64);
        nx  += __shfl_down(nx,  off, 64);
        ny  += __shfl_down(ny,  off, 64);
    }
    __shared__ float s[3][4];
    int lane = threadIdx.x & 63, wv = threadIdx.x >> 6;
    if (lane == 0) { s[0][wv] = dot; s[1][wv] = nx; s[2][wv] = ny; }
    __syncthreads();
    if (threadIdx.x == 0) {
        float D = 0.f, NX = 0.f, NY = 0.f;
        for (int w = 0; w < 4; ++w) { D += s[0][w]; NX += s[1][w]; NY += s[2][w]; }
        partials[blockIdx.x * 3 + 0] = D;
        partials[blockIdx.x * 3 + 1] = NX;
        partials[blockIdx.x * 3 + 2] = NY;
    }
}

// ---------- hierarchical scan ----------
__global__ void scanA_kernel(const int* __restrict__ cnt, int* __restrict__ tmp,
                             int* __restrict__ bsum, int m) {
    __shared__ int s[256];
    int i = blockIdx.x * 256 + threadIdx.x;
    int v = (i < m) ? cnt[i] : 0;
    s[threadIdx.x] = v;
    __syncthreads();
    for (int d = 1; d < 256; d <<= 1) {
        int t = (threadIdx.x >= (unsigned)d) ? s[threadIdx.x - d] : 0;
        __syncthreads();
        s[threadIdx.x] += t;
        __syncthreads();
    }
    if (i < m) tmp[i] = s[threadIdx.x] - v;          // exclusive within block
    if (threadIdx.x == 255) bsum[blockIdx.x] = s[255];
}

// scanB also finalizes sim (partials are ready — prep completed earlier in stream)
__global__ void scanB_kernel(int* __restrict__ bsum, int* __restrict__ boff, int nb,
                             const float* __restrict__ partials, int np,
                             float* __restrict__ out_sim) {
    __shared__ int s[512];
    int v = (threadIdx.x < nb) ? bsum[threadIdx.x] : 0;
    s[threadIdx.x] = v;
    __syncthreads();
    for (int d = 1; d < 512; d <<= 1) {
        int t = (threadIdx.x >= (unsigned)d) ? s[threadIdx.x - d] : 0;
        __syncthreads();
        s[threadIdx.x] += t;
        __syncthreads();
    }
    if (threadIdx.x < nb) boff[threadIdx.x] = s[threadIdx.x] - v;   // exclusive
    // sim finalize on wave 0
    if (threadIdx.x < 64) {
        double dot = 0.0, nxs = 0.0, nys = 0.0;
        for (int i = threadIdx.x; i < np; i += 64) {
            dot += (double)partials[i * 3 + 0];
            nxs += (double)partials[i * 3 + 1];
            nys += (double)partials[i * 3 + 2];
        }
        for (int off = 32; off > 0; off >>= 1) {
            dot += __shfl_down(dot, off, 64);
            nxs += __shfl_down(nxs, off, 64);
            nys += __shfl_down(nys, off, 64);
        }
        if (threadIdx.x == 0)
            *out_sim = (float)(dot / (sqrt(nxs) * sqrt(nys)));
    }
}

__global__ void scanC_kernel(const int* tmp, const int* __restrict__ boff,
                             int* __restrict__ off, int* cur, int m, int e_tot) {
    int i = blockIdx.x * 256 + threadIdx.x;
    if (i < m) {
        int o = tmp[i] + boff[i >> 8];
        off[i] = o;
        cur[i] = o;
    }
    if (i == 0) off[m] = e_tot;
}

// ---------- dense scatter ----------
__global__ void scatter_kernel(const int* __restrict__ sub_rows, const int* __restrict__ sub_cols,
                               const float* __restrict__ sub_vals, int e_sub,
                               const int* __restrict__ sup_rows, const int* __restrict__ sup_cols,
                               const float* __restrict__ sup_vals, int e_sup,
                               int* __restrict__ cur, int2* __restrict__ pk, int nrows) {
    int i = blockIdx.x * blockDim.x + threadIdx.x;
    int e_tot = e_sub + e_sup;
    if (i >= e_tot) return;
    int r, c; float v;
    if (i < e_sub) { r = sub_rows[i]; c = sub_cols[i]; v = sub_vals[i]; }
    else { int k = i - e_sub; r = nrows + sup_rows[k]; c = sup_cols[k]; v = sup_vals[k]; }
    int pos = atomicAdd(&cur[r], 1);
    pk[pos] = make_int2(c, __float_as_int(v));
}

// ---------- row accumulate: wave per row, diff for sub, 4-wide unrolled gathers ----------
__global__ void row_kernel(const int* __restrict__ offs, const int2* __restrict__ pk,
                           const float* __restrict__ diff, const float* __restrict__ old_act,
                           float* __restrict__ out, int nrows) {
    int wv = threadIdx.x >> 6, lane = threadIdx.x & 63;
    int r = blockIdx.x * (blockDim.x >> 6) + wv;
    if (r >= nrows) return;
    const int d0 = lane * 2;
    float a0 = 0.f, a1 = 0.f;

    // sub edges: v * diff[c]
    {
        int b = offs[r], e = offs[r + 1];
        int j = b;
        for (; j + 4 <= e; j += 4) {
            int2 p0 = pk[j], p1 = pk[j + 1], p2 = pk[j + 2], p3 = pk[j + 3];
            float2 y0 = *(const float2*)(diff + (size_t)p0.x * DIM + d0);
            float2 y1 = *(const float2*)(diff + (size_t)p1.x * DIM + d0);
            float2 y2 = *(const float2*)(diff + (size_t)p2.x * DIM + d0);
            float2 y3 = *(const float2*)(diff + (size_t)p3.x * DIM + d0);
            a0 += __int_as_float(p0.y) * y0.x; a1 += __int_as_float(p0.y) * y0.y;
            a0 += __int_as_float(p1.y) * y1.x; a1 += __int_as_float(p1.y) * y1.y;
            a0 += __int_as_float(p2.y) * y2.x; a1 += __int_as_float(p2.y) * y2.y;
            a0 += __int_as_float(p3.y) * y3.x; a1 += __int_as_float(p3.y) * y3.y;
        }
        for (; j < e; ++j) {
            int2 p = pk[j];
            float2 y = *(const float2*)(diff + (size_t)p.x * DIM + d0);
            a0 += __int_as_float(p.y) * y.x;
            a1 += __int_as_float(p.y) * y.y;
        }
    }
    // sup edges: v * old_act[c]
    {
        int b = offs[nrows + r], e = offs[nrows + r + 1];
        int j = b;
        for (; j + 4 <= e; j += 4) {
            int2 p0 = pk[j], p1 = pk[j + 1], p2 = pk[j + 2], p3 = pk[j + 3];
            float2 y0 = *(const float2*)(old_act + (size_t)p0.x * DIM + d0);
            float2 y1 = *(const float2*)(old_act + (size_t)p1.x * DIM + d0);
            float2 y2 = *(const float2*)(old_act + (size_t)p2.x * DIM + d0);
            float2 y3 = *(const float2*)(old_act + (size_t)p3.x * DIM + d0);
            a0 += __int_as_float(p0.y) * y0.x; a1 += __int_as_float(p0.y) * y0.y;
            a0 += __int_as_float(p1.y) * y1.x; a1 += __int_as_float(p1.y) * y1.y;
            a0 += __int_as_float(p2.y) * y2.x; a1 += __int_as_float(p2.y) * y2.y;
            a0 += __int_as_float(p3.y) * y3.x; a1 += __int_as_float(p3.y) * y3.y;
        }
        for (; j < e; ++j) {
            int2 p = pk[j];
            float2 y = *(const float2*)(old_act + (size_t)p.x * DIM + d0);
            a0 += __int_as_float(p.y) * y.x;
            a1 += __int_as_float(p.y) * y.y;
        }
    }
    *(float2*)(out + (size_t)r * DIM + d0) = make_float2(a0, a1);
}

// ---------- fallback (atomic path, any ws size) ----------
__global__ void zero_out_kernel(float* __restrict__ out, int n) {
    int i = blockIdx.x * blockDim.x + threadIdx.x;
    if (i < n) out[i] = 0.f;
}
__global__ void sim_atomic_kernel(const float* __restrict__ inputs,
                                  const float* __restrict__ old_act,
                                  const int* __restrict__ fields,
                                  float* __restrict__ out_sim, int n2) {
    // single-block version (slow but tiny ws): grid = 1
    __shared__ double sd[3];
    if (threadIdx.x == 0) { sd[0] = 0; sd[1] = 0; sd[2] = 0; }
    __syncthreads();
    float dot = 0.f, nx = 0.f, ny = 0.f;
    for (int i = threadIdx.x; i < n2; i += blockDim.x) {
        int idx = i * 2;
        int b = idx >> 7, d = idx & (DIM - 1);
        float2 x = *(const float2*)(inputs + idx);
        int f = fields[b];
        float2 y = *(const float2*)(old_act + (size_t)f * DIM + d);
        dot += x.x * y.x + x.y * y.y;
        nx  += x.x * x.x + x.y * x.y;
        ny  += y.x * y.x + y.y * y.y;
    }
    for (int off = 32; off > 0; off >>= 1) {
        dot += __shfl_down(dot, off, 64);
        nx  += __shfl_down(nx,  off, 64);
        ny  += __shfl_down(ny,  off, 64);
    }
    if ((threadIdx.x & 63) == 0) {
        atomicAdd(&sd[0], (double)dot);
        atomicAdd(&sd[1], (double)nx);
        atomicAdd(&sd[2], (double)ny);
    }
    __syncthreads();
    if (threadIdx.x == 0)
        *out_sim = (float)(sd[0] / (sqrt(sd[1]) * sqrt(sd[2])));
}
__global__ void spmm_sub_atomic(const int* __restrict__ rows, const int* __restrict__ cols,
                                const float* __restrict__ vals, const float* __restrict__ inputs,
                                const float* __restrict__ old_act, const int* __restrict__ fields,
                                float* __restrict__ out, int ne) {
    int t = blockIdx.x * blockDim.x + threadIdx.x;
    int e = t >> 6, lane = t & 63;
    if (e >= ne) return;
    int r = rows[e], c = cols[e];
    float v = vals[e];
    int f = fields[c];
    int d0 = lane * 2;
    const float2 x = *(const float2*)(inputs  + (size_t)c * DIM + d0);
    const float2 y = *(const float2*)(old_act + (size_t)f * DIM + d0);
    float* o = out + (size_t)r * DIM + d0;
    atomicAdd(o,     v * (x.x - y.x));
    atomicAdd(o + 1, v * (x.y - y.y));
}
__global__ void spmm_sup_atomic(const int* __restrict__ rows, const int* __restrict__ cols,
                                const float* __restrict__ vals, const float* __restrict__ old_act,
                                float* __restrict__ out, int ne) {
    int t = blockIdx.x * blockDim.x + threadIdx.x;
    int e = t >> 6, lane = t & 63;
    if (e >= ne) return;
    int r = rows[e], c = cols[e];
    float v = vals[e];
    int d0 = lane * 2;
    const float2 y = *(const float2*)(old_act + (size_t)c * DIM + d0);
    float* o = out + (size_t)r * DIM + d0;
    atomicAdd(o,     v * y.x);
    atomicAdd(o + 1, v * y.y);
}

extern "C" void kernel_launch(void* const* d_in, const int* in_sizes, int n_in,
                              void* d_out, int out_size, void* d_ws, size_t ws_size,
                              hipStream_t stream) {
    const float* inputs   = (const float*)d_in[0];
    const float* old_act  = (const float*)d_in[1];
    const int*   fields   = (const int*)d_in[2];
    const int*   sub_rows = (const int*)d_in[3];
    const int*   sub_cols = (const int*)d_in[4];
    const float* sub_vals = (const float*)d_in[5];
    const int*   sup_rows = (const int*)d_in[6];
    const int*   sup_cols = (const int*)d_in[7];
    const float* sup_vals = (const float*)d_in[8];

    const int n     = in_sizes[0];     // BATCH * DIM
    const int nrows = n / DIM;         // BATCH
    const int e_sub = in_sizes[3];
    const int e_sup = in_sizes[6];
    const int e_tot = e_sub + e_sup;
    const int m     = 2 * nrows;
    const int nblkA = (m + 255) / 256;

    float* out = (float*)d_out;
    char*  ws  = (char*)d_ws;

    // ---- workspace layout ----
    size_t off_part = 0;                                     // f32[PREP_GRID*3]
    size_t off_cnt  = (PREP_GRID * 3 * 4 + 63) & ~(size_t)63;// int[m]
    size_t off_tmp  = off_cnt + (size_t)m * 4;               // int[m] (cur alias)
    size_t off_offs = off_tmp + (size_t)m * 4;               // int[m+1]
    size_t off_bsum = off_offs + (size_t)(m + 1) * 4;        // int[512]
    size_t off_boff = off_bsum + 2048;                       // int[512]
    size_t off_pk   = (off_boff + 2048 + 7) & ~(size_t)7;    // int2[e_tot]
    size_t off_diff = off_pk + (size_t)e_tot * 8;            // f32[n]
    size_t need     = off_diff + (size_t)n * 4;

    if (ws_size >= need && nblkA <= 512) {
        float* partials = (float*)(ws + off_part);
        int*   cnt      = (int*)(ws + off_cnt);
        int*   tmp      = (int*)(ws + off_tmp);
        int*   offs     = (int*)(ws + off_offs);
        int*   bsum     = (int*)(ws + off_bsum);
        int*   boff     = (int*)(ws + off_boff);
        int2*  pk       = (int2*)(ws + off_pk);
        float* diff     = (float*)(ws + off_diff);

        hipMemsetAsync(cnt, 0, (size_t)m * 4, stream);

        prep_kernel<<<PREP_GRID, TPB, 0, stream>>>(
            inputs, old_act, fields, sub_rows, e_sub, sup_rows, e_sup,
            cnt, partials, diff, nrows, n / 2);

        scanA_kernel<<<nblkA, 256, 0, stream>>>(cnt, tmp, bsum, m);
        scanB_kernel<<<1, 512, 0, stream>>>(bsum, boff, nblkA,
                                            partials, PREP_GRID, out + n);
        scanC_kernel<<<nblkA, 256, 0, stream>>>(tmp, boff, offs, tmp, m, e_tot);

        scatter_kernel<<<(e_tot + 255) / 256, 256, 0, stream>>>(
            sub_rows, sub_cols, sub_vals, e_sub,
            sup_rows, sup_cols, sup_vals, e_sup, tmp, pk, nrows);

        row_kernel<<<(nrows + 3) / 4, TPB, 0, stream>>>(
            offs, pk, diff, old_act, out, nrows);
    } else {
        // fallback: atomic path, needs no workspace
        zero_out_kernel<<<(n + 255) / 256, 256, 0, stream>>>(out, n);
        {
            long long threads = (long long)e_sub * 64;
            spmm_sub_atomic<<<(int)((threads + 255) / 256), 256, 0, stream>>>(
                sub_rows, sub_cols, sub_vals, inputs, old_act, fields, out, e_sub);
        }
        {
            long long threads = (long long)e_sup * 64;
            spmm_sup_atomic<<<(int)((threads + 255) / 256), 256, 0, stream>>>(
                sup_rows, sup_cols, sup_vals, old_act, out, e_sup);
        }
        sim_atomic_kernel<<<1, 1024, 0, stream>>>(inputs, old_act, fields, out + n, n / 2);
    }
}